// Round 19
// baseline (183.481 us; speedup 1.0000x reference)
//
#include <hip/hip_runtime.h>
#include <math.h>

#define NN 10000
#define NE 160000
#define NB 4
#define NH 4
#define ND 256
#define NT (NN * 16)        // (n,b,h) triples
#define NM 40000            // GEMM rows (b*NN+n)

typedef _Float16 f16;
typedef _Float16 half8 __attribute__((ext_vector_type(8)));
typedef _Float16 h2 __attribute__((ext_vector_type(2)));
typedef float f32x4 __attribute__((ext_vector_type(4)));

union H4 { uint2 u; f16 h[4]; };
union U2H { unsigned u; h2 h; };
union U4H { uint4 u; h2 h[4]; };

__device__ __forceinline__ void gload_lds16(const void* g, void* l) {
  __builtin_amdgcn_global_load_lds((const __attribute__((address_space(1))) void*)g,
                                   (__attribute__((address_space(3))) void*)l, 16, 0, 0);
}

// ---------------- CSR build ----------------
__global__ __launch_bounds__(256) void k_deg(const int* __restrict__ dst, int* __restrict__ deg) {
  int e = blockIdx.x * 256 + threadIdx.x;
  if (e < NE) atomicAdd(&deg[dst[e]], 1);
}

// 3-barrier scan: 10 elems/thread serial + wave shfl scan + cross-wave combine
__global__ __launch_bounds__(1024) void k_scan2(const int* __restrict__ deg, int* __restrict__ offs) {
  __shared__ int wsum[16];
  __shared__ int wbase[17];
  const int t = threadIdx.x, lane = t & 63, wv = t >> 6;
  int v[10];
  int s = 0;
  if (t < 1000) {
#pragma unroll
    for (int i = 0; i < 10; ++i) { v[i] = deg[t * 10 + i]; s += v[i]; }
  }
  int inc = s;
#pragma unroll
  for (int k = 1; k < 64; k <<= 1) {
    int u = __shfl_up(inc, k);
    if (lane >= k) inc += u;
  }
  if (lane == 63) wsum[wv] = inc;
  __syncthreads();
  if (t == 0) {
    int c = 0;
#pragma unroll
    for (int i = 0; i < 16; ++i) { wbase[i] = c; c += wsum[i]; }
    wbase[16] = c;
    offs[NN] = c;
  }
  __syncthreads();
  if (t < 1000) {
    int c = wbase[wv] + inc - s;   // exclusive base for this thread
#pragma unroll
    for (int i = 0; i < 10; ++i) { offs[t * 10 + i] = c; c += v[i]; }
  }
}

__global__ __launch_bounds__(256) void k_scatter(const int* __restrict__ src, const int* __restrict__ dst,
                                                 const float* __restrict__ w, const int* __restrict__ offs,
                                                 int* __restrict__ cursor, int* __restrict__ csr_src,
                                                 float* __restrict__ csr_w) {
  int e = blockIdx.x * 256 + threadIdx.x;
  if (e < NE) {
    int d = dst[e];
    int slot = offs[d] + atomicAdd(&cursor[d], 1);
    csr_src[slot] = src[e];
    csr_w[slot] = w[e];
  }
}

// ---------------- prep: both layers' fused weights + attn rows + mlp cvt ----------------
__global__ __launch_bounds__(256) void k_prep(const float* __restrict__ fc_w, const float* __restrict__ ofc_w,
                                              const float* __restrict__ al, const float* __restrict__ ar,
                                              const float* __restrict__ mlp_w,
                                              f16* __restrict__ fwh2, f16* __restrict__ alfh2,
                                              f16* __restrict__ mlph) {
  int r = blockIdx.x;
  int d = threadIdx.x;
  if (r < 512) {
    int l = r >> 8, rr = r & 255;
    int h = rr >> 6, o = rr & 63;
    const float* fcl = fc_w + (size_t)l * 65536;
    const float* ow = ofc_w + (size_t)l * 4096;
    float acc = 0.f;
    for (int f = 0; f < 64; ++f)
      acc = fmaf(ow[(o << 6) + f], fcl[(((h << 6) + f) << 8) + d], acc);
    fwh2[((size_t)l << 16) + (rr << 8) + d] = (f16)acc;
  } else if (r < 544) {
    int rr = r - 512;
    int l = rr >> 4, q = rr & 15;
    const float* fcl = fc_w + (size_t)l * 65536;
    float acc = 0.f;
    if (q < 8) {
      int h = q & 3;
      const float* a = ((q < 4) ? al : ar) + (size_t)l * NH * 64;
      for (int f = 0; f < 64; ++f)
        acc = fmaf(a[(h << 6) + f], fcl[(((h << 6) + f) << 8) + d], acc);
    }
    alfh2[((size_t)l << 12) + (q << 8) + d] = (f16)acc;
  } else {
    int i = (r - 544) * 256 + d;     // 32768 quads
    float4 v = *(const float4*)(mlp_w + (size_t)i * 4);
    H4 h;
    h.h[0] = (f16)v.x; h.h[1] = (f16)v.y; h.h[2] = (f16)v.z; h.h[3] = (f16)v.w;
    *(uint2*)(mlph + (size_t)i * 4) = h.u;
  }
}

// ---------------- MFMA fp16 GEMM, 64x128 tile, K-STEP 64 (+el/er fusion, +fp32 cvt) ----------------
// BK=64 halves barrier count (R17: -3.5us). Epilogue = R14-proven (non-swapped).
template<int OUTH, int EL, int CVT>
__global__ __launch_bounds__(256) void k_gemm_f16(
    const void* __restrict__ A, int lda, int K,
    const f16* __restrict__ W,
    const float* __restrict__ bias,
    void* __restrict__ outp, int ldo,
    const f16* __restrict__ alfh, float* __restrict__ el2, float* __restrict__ er2)
{
  __shared__ __align__(16) f16 As[64 * 64];    // 8KB
  __shared__ __align__(16) f16 Bs[128 * 64];   // 16KB
  const int tid = threadIdx.x;
  const int lane = tid & 63;
  const int w = tid >> 6;
  const int wr = w >> 1, wc = w & 1;
  const int ra0 = blockIdx.x * 64;
  const int c0 = blockIdx.y * 128;
  const int l8r = lane >> 3;           // 0..7 row within 8-row panel
  const int l8o = (lane & 7) * 8;      // 0..56 k-offset (halfs)

  f32x4 acc[2][4];
#pragma unroll
  for (int mr = 0; mr < 2; ++mr)
#pragma unroll
    for (int nr = 0; nr < 4; ++nr) acc[mr][nr] = (f32x4)0.f;
  f32x4 accel[2];
  accel[0] = (f32x4)0.f; accel[1] = (f32x4)0.f;
  const bool doEl = EL && (blockIdx.y == 0) && (wc == 0);

  const int fr = lane & 15;
  const int fg = (lane >> 4) * 8;

  for (int k0 = 0; k0 < K; k0 += 64) {
    if (CVT) {
      // reg-staged fp32 -> fp16; chunk c covers (row=c>>3, koct=c&7), dest As+c*8
      const float* sf = (const float*)A;
#pragma unroll
      for (int i = 0; i < 2; ++i) {
        int chunk = tid + i * 256;           // 512 chunks of 8 halfs
        int row = chunk >> 3;
        int kk = k0 + (chunk & 7) * 8;
        const float* ps = (kk < 128) ? sf + (size_t)(ra0 + row) * 128 + kk
                                     : sf + (size_t)(NM + ra0 + row) * 128 + (kk - 128);
        float4 p0 = *(const float4*)ps;
        float4 p1 = *(const float4*)(ps + 4);
        half8 hv;
        hv[0] = (f16)p0.x; hv[1] = (f16)p0.y; hv[2] = (f16)p0.z; hv[3] = (f16)p0.w;
        hv[4] = (f16)p1.x; hv[5] = (f16)p1.y; hv[6] = (f16)p1.z; hv[7] = (f16)p1.w;
        *(half8*)(As + chunk * 8) = hv;
      }
    } else {
      const f16* Af = (const f16*)A;
      // wave w stages rows 16w..16w+15 (2 issues of 8 rows x 128B)
      gload_lds16(Af + (size_t)(ra0 + 16 * w + l8r) * lda + k0 + l8o, As + w * 1024);
      gload_lds16(Af + (size_t)(ra0 + 16 * w + 8 + l8r) * lda + k0 + l8o, As + w * 1024 + 512);
    }
    // wave w stages cols 32w..32w+31 (4 issues of 8 cols x 128B)
#pragma unroll
    for (int j = 0; j < 4; ++j)
      gload_lds16(W + (size_t)(c0 + 32 * w + j * 8 + l8r) * K + k0 + l8o,
                  Bs + w * 2048 + j * 512);
    __syncthreads();

#pragma unroll
    for (int kk = 0; kk < 2; ++kk) {
      half8 af[2], bf[4];
#pragma unroll
      for (int mr = 0; mr < 2; ++mr)
        af[mr] = *(const half8*)(As + (wr * 32 + mr * 16 + fr) * 64 + kk * 32 + fg);
#pragma unroll
      for (int nr = 0; nr < 4; ++nr)
        bf[nr] = *(const half8*)(Bs + (wc * 64 + nr * 16 + fr) * 64 + kk * 32 + fg);
#pragma unroll
      for (int mr = 0; mr < 2; ++mr)
#pragma unroll
        for (int nr = 0; nr < 4; ++nr)
          acc[mr][nr] = __builtin_amdgcn_mfma_f32_16x16x32_f16(af[mr], bf[nr], acc[mr][nr], 0, 0, 0);
      if (doEl) {
        half8 bal = *(const half8*)(alfh + fr * 256 + k0 + kk * 32 + fg);   // L1-hot 8KB
#pragma unroll
        for (int mr = 0; mr < 2; ++mr)
          accel[mr] = __builtin_amdgcn_mfma_f32_16x16x32_f16(af[mr], bal, accel[mr], 0, 0, 0);
      }
    }
    __syncthreads();
  }

  const int r0 = (lane >> 4) * 4;
#pragma unroll
  for (int nr = 0; nr < 4; ++nr) {
    int col = c0 + wc * 64 + nr * 16 + fr;
    float bv = bias ? bias[col] : 0.f;
#pragma unroll
    for (int mr = 0; mr < 2; ++mr) {
      f32x4 v = acc[mr][nr];
#pragma unroll
      for (int r = 0; r < 4; ++r) {
        int ra = ra0 + wr * 32 + mr * 16 + r0 + r;
        float val = v[r] + bv;
        if (OUTH) ((f16*)outp)[(size_t)ra * ldo + col] = (f16)val;
        else      ((float*)outp)[(size_t)ra * ldo + col] = val;
      }
    }
  }
  if (doEl && fr < 8) {
#pragma unroll
    for (int mr = 0; mr < 2; ++mr) {
#pragma unroll
      for (int r = 0; r < 4; ++r) {
        int ra = ra0 + wr * 32 + mr * 16 + r0 + r;
        int n = ra % NN, b = ra / NN;
        int tb = (n << 4) + (b << 2);
        float val = accel[mr][r];
        if (fr < 4) el2[tb + fr] = val;
        else        er2[tb + (fr - 4)] = val;
      }
    }
  }
}

// ---------------- fused softmax + aggregate: wave per (n,b) ----------------
// R18 structure; aggregate deepened to 16 edges/iter = 8 independent dwordx4
// gathers in flight (R18: 2->4 outstanding gave -9.3us total; latency gap remains).
// Zero-filled 64-slot staging keeps full 16-edge groups tail-safe (alpha=0, src=0).
__global__ __launch_bounds__(256) void k_edge8(
    const f16* __restrict__ featW_b, const float* __restrict__ el2, const float* __restrict__ er2,
    const int* __restrict__ csr_src, const float* __restrict__ csr_w,
    const int* __restrict__ offs, const float* __restrict__ b2, f16* __restrict__ outh)
{
  __shared__ __align__(16) unsigned aalp[4][64][4];  // [wave][edge][head] splat pairs
  __shared__ unsigned asrc[4][64];
  __shared__ float aw[4][64];
  __shared__ float sls[4][4];
  __shared__ float sinvs[4][4];
  const int t = threadIdx.x;
  const int w = t >> 6, lane = t & 63;
  const int b = blockIdx.x & 3;
  const int n = (blockIdx.x >> 2) * 4 + w;
  const int s0 = offs[n], s1 = offs[n + 1];
  const int es = lane >> 2;            // 0..15 edge slot
  const int sh = lane & 3;             // head
  const float erv = er2[(n << 4) + (b << 2) + sh];
  const int hl = lane & 31;            // lane within half
  const int eh = lane >> 5;            // which edge of the pair
  const int h8 = hl >> 3;              // head (8 ch/lane)
  const int ch0 = hl << 3;             // first channel owned
  const f16* fW = featW_b + ((size_t)b * NN << 8);

  float m = -INFINITY, srun = 0.f;
  h2 a0 = {(f16)0.f, (f16)0.f}, a1 = a0, a2 = a0, a3 = a0;

  for (int c0 = s0; c0 < s1; c0 += 64) {
    const int csz = min(64, s1 - c0);
    // unconditional zero-fill staging (tail-safe)
    unsigned sv = 0;
    float wv = 0.f;
    if (lane < csz) {
      sv = (unsigned)csr_src[c0 + lane];
      wv = csr_w[c0 + lane];
    }
    asrc[w][lane] = sv;
    aw[w][lane] = wv;
    // ---- score phase ----
    float sc[4];
#pragma unroll
    for (int i = 0; i < 4; ++i) {
      int e = es + 16 * i;
      if (e < csz) {
        int src = (int)asrc[w][e];
        float x = el2[(src << 4) + (b << 2) + sh] + erv;
        x = (x > 0.f) ? x : 0.1f * x;
        sc[i] = x * aw[w][e];
      } else sc[i] = -INFINITY;
    }
    float mc = fmaxf(fmaxf(sc[0], sc[1]), fmaxf(sc[2], sc[3]));
#pragma unroll
    for (int k = 4; k <= 32; k <<= 1) mc = fmaxf(mc, __shfl_xor(mc, k));
    float mn = fmaxf(m, mc);
    float sl = (m == -INFINITY) ? 0.f : __expf(m - mn);
    float ps = 0.f;
#pragma unroll
    for (int i = 0; i < 4; ++i) {
      int e = es + 16 * i;
      float a = (e < csz) ? __expf(sc[i] - mn) : 0.f;
      ps += a;
      f16 ah = (f16)a;
      U2H sp; sp.h[0] = ah; sp.h[1] = ah;
      aalp[w][e][sh] = sp.u;           // all 64 slots written -> tail-safe
    }
#pragma unroll
    for (int k = 4; k <= 32; k <<= 1) ps += __shfl_xor(ps, k);
    srun = srun * sl + ps;
    m = mn;
    if (es == 0) sls[w][sh] = sl;      // same-wave LDS handoff (no barrier)
    // ---- aggregate: 16 edges/iter, 8 independent gathers in flight ----
    float slA = sls[w][h8];
    f16 slh = (f16)slA;
    h2 slv = {slh, slh};
    a0 *= slv; a1 *= slv; a2 *= slv; a3 *= slv;
    for (int e = 0; e < csz; e += 16) {
      unsigned su_[8];
      U2H al_[8];
      U4H f_[8];
#pragma unroll
      for (int i = 0; i < 8; ++i) {
        const int ei = e + 2 * i + eh;           // <= 63 always (zero-filled tail)
        su_[i] = asrc[w][ei];
        al_[i].u = aalp[w][ei][h8];
      }
#pragma unroll
      for (int i = 0; i < 8; ++i)
        f_[i].u = *(const uint4*)(fW + ((size_t)su_[i] << 8) + ch0);
#pragma unroll
      for (int i = 0; i < 8; ++i) {
        a0 += f_[i].h[0] * al_[i].h;
        a1 += f_[i].h[1] * al_[i].h;
        a2 += f_[i].h[2] * al_[i].h;
        a3 += f_[i].h[3] * al_[i].h;
      }
    }
  }
  // combine the two half-wave edge streams
  U2H u0, u1, u2, u3;
  u0.h = a0; u1.h = a1; u2.h = a2; u3.h = a3;
  U2H p0, p1, p2, p3;
  p0.u = (unsigned)__shfl_xor((int)u0.u, 32);
  p1.u = (unsigned)__shfl_xor((int)u1.u, 32);
  p2.u = (unsigned)__shfl_xor((int)u2.u, 32);
  p3.u = (unsigned)__shfl_xor((int)u3.u, 32);
  a0 += p0.h; a1 += p1.h; a2 += p2.h; a3 += p3.h;

  float invs = (s1 > s0) ? 1.f / srun : 0.f;     // uniform across sh-group lanes
  if (es == 0) sinvs[w][sh] = invs;

  if (lane < 32) {
    const float invv = sinvs[w][h8];
    const float4 bv0 = *(const float4*)(b2 + ((hl & 7) << 3));
    const float4 bv1 = *(const float4*)(b2 + ((hl & 7) << 3) + 4);
    H4 o01, o23;
    o01.h[0] = (f16)fmaxf(fmaf((float)a0[0], invv, bv0.x), 0.f);
    o01.h[1] = (f16)fmaxf(fmaf((float)a0[1], invv, bv0.y), 0.f);
    o01.h[2] = (f16)fmaxf(fmaf((float)a1[0], invv, bv0.z), 0.f);
    o01.h[3] = (f16)fmaxf(fmaf((float)a1[1], invv, bv0.w), 0.f);
    o23.h[0] = (f16)fmaxf(fmaf((float)a2[0], invv, bv1.x), 0.f);
    o23.h[1] = (f16)fmaxf(fmaf((float)a2[1], invv, bv1.y), 0.f);
    o23.h[2] = (f16)fmaxf(fmaf((float)a3[0], invv, bv1.z), 0.f);
    o23.h[3] = (f16)fmaxf(fmaf((float)a3[1], invv, bv1.w), 0.f);
    uint4 ov;
    ov.x = o01.u.x; ov.y = o01.u.y; ov.z = o23.u.x; ov.w = o23.u.y;
    *(uint4*)(outh + ((size_t)(b * NN + n) << 9) + ch0) = ov;
  }
}

// ---------------- launch ----------------
extern "C" void kernel_launch(void* const* d_in, const int* in_sizes, int n_in,
                              void* d_out, int out_size, void* d_ws, size_t ws_size,
                              hipStream_t stream) {
  const float* sol    = (const float*)d_in[0];
  const float* w      = (const float*)d_in[1];
  const float* fc_w   = (const float*)d_in[2];
  const float* attn_l = (const float*)d_in[3];
  const float* attn_r = (const float*)d_in[4];
  const float* ofc_w  = (const float*)d_in[5];
  const float* ofc_b  = (const float*)d_in[6];
  const float* mlp_w  = (const float*)d_in[7];
  const float* mlp_b  = (const float*)d_in[8];
  const int*   d_src  = (const int*)d_in[9];
  const int*   d_dst  = (const int*)d_in[10];
  float* out = (float*)d_out;

  char* p = (char*)d_ws;
  auto alloc = [&](size_t bytes) { char* r = p; p += (bytes + 255) & ~(size_t)255; return r; };
  f16*   out01h  = (f16*)alloc((size_t)(NM + 128) * 512 * 2);
  f16*   featWb  = (f16*)alloc((size_t)NM * 256 * 2);          // [b*NN+n][256] row-major
  f16*   fwh2    = (f16*)alloc((size_t)2 * ND * ND * 2);
  f16*   alfh2   = (f16*)alloc((size_t)2 * 16 * ND * 2);       // rows 8-15 zero
  f16*   mlph    = (f16*)alloc((size_t)ND * 512 * 2);
  float* el2     = (float*)alloc((size_t)NT * 4);              // [NN][16]
  float* er2     = (float*)alloc((size_t)NT * 4);
  int*   degcur  = (int*)alloc((size_t)(2 * NN) * 4);          // deg[NN] + cursor[NN], one memset
  int*   deg     = degcur;
  int*   cursor  = degcur + NN;
  int*   offs    = (int*)alloc((size_t)(NN + 1) * 4);
  int*   csr_src = (int*)alloc((size_t)NE * 4);
  float* csr_w   = (float*)alloc((size_t)NE * 4);
  if ((size_t)(p - (char*)d_ws) > ws_size) return;

  hipMemsetAsync(degcur, 0, (size_t)(2 * NN) * 4, stream);
  k_deg<<<NE / 256, 256, 0, stream>>>(d_dst, deg);
  k_scan2<<<1, 1024, 0, stream>>>(deg, offs);
  k_scatter<<<NE / 256, 256, 0, stream>>>(d_src, d_dst, w, offs, cursor, csr_src, csr_w);

  k_prep<<<672, 256, 0, stream>>>(fc_w, ofc_w, attn_l, attn_r, mlp_w, fwh2, alfh2, mlph);

  for (int l = 0; l < 2; ++l) {
    const f16* fwh  = fwh2 + ((size_t)l << 16);
    const f16* alfh = alfh2 + ((size_t)l << 12);
    if (l == 0) {
      k_gemm_f16<1, 1, 1><<<dim3(NM / 64, ND / 128), 256, 0, stream>>>(
          sol, 128, 256, fwh, nullptr, featWb, 256, alfh, el2, er2);
    } else {
      k_gemm_f16<1, 1, 0><<<dim3(NM / 64, ND / 128), 256, 0, stream>>>(
          out01h, 512, 256, fwh, nullptr, featWb, 256, alfh, el2, er2);
    }
    k_edge8<<<(NN / 4) * 4, 256, 0, stream>>>(featWb, el2, er2, csr_src, csr_w, offs,
                                              ofc_b + (size_t)l * 64, out01h + (l == 0 ? 0 : 256));
  }

  k_gemm_f16<0, 0, 0><<<dim3(NM / 64, ND / 128), 256, 0, stream>>>(
      out01h, 512, 512, mlph, mlp_b, out, 256, nullptr, nullptr, nullptr);
}

// Round 20
// 172.117 us; speedup vs baseline: 1.0660x; 1.0660x over previous
//
#include <hip/hip_runtime.h>
#include <math.h>

#define NN 10000
#define NE 160000
#define NB 4
#define NH 4
#define ND 256
#define NT (NN * 16)        // (n,b,h) triples
#define NM 40000            // GEMM rows (b*NN+n)

typedef _Float16 f16;
typedef _Float16 half8 __attribute__((ext_vector_type(8)));
typedef _Float16 h2 __attribute__((ext_vector_type(2)));
typedef float f32x4 __attribute__((ext_vector_type(4)));

union H4 { uint2 u; f16 h[4]; };
union U2H { unsigned u; h2 h; };
union U4H { uint4 u; h2 h[4]; };

__device__ __forceinline__ void gload_lds16(const void* g, void* l) {
  __builtin_amdgcn_global_load_lds((const __attribute__((address_space(1))) void*)g,
                                   (__attribute__((address_space(3))) void*)l, 16, 0, 0);
}

// ---------------- CSR build ----------------
__global__ __launch_bounds__(256) void k_deg(const int* __restrict__ dst, int* __restrict__ deg) {
  int e = blockIdx.x * 256 + threadIdx.x;
  if (e < NE) atomicAdd(&deg[dst[e]], 1);
}

// 3-barrier scan: 10 elems/thread serial + wave shfl scan + cross-wave combine
__global__ __launch_bounds__(1024) void k_scan2(const int* __restrict__ deg, int* __restrict__ offs) {
  __shared__ int wsum[16];
  __shared__ int wbase[17];
  const int t = threadIdx.x, lane = t & 63, wv = t >> 6;
  int v[10];
  int s = 0;
  if (t < 1000) {
#pragma unroll
    for (int i = 0; i < 10; ++i) { v[i] = deg[t * 10 + i]; s += v[i]; }
  }
  int inc = s;
#pragma unroll
  for (int k = 1; k < 64; k <<= 1) {
    int u = __shfl_up(inc, k);
    if (lane >= k) inc += u;
  }
  if (lane == 63) wsum[wv] = inc;
  __syncthreads();
  if (t == 0) {
    int c = 0;
#pragma unroll
    for (int i = 0; i < 16; ++i) { wbase[i] = c; c += wsum[i]; }
    wbase[16] = c;
    offs[NN] = c;
  }
  __syncthreads();
  if (t < 1000) {
    int c = wbase[wv] + inc - s;   // exclusive base for this thread
#pragma unroll
    for (int i = 0; i < 10; ++i) { offs[t * 10 + i] = c; c += v[i]; }
  }
}

__global__ __launch_bounds__(256) void k_scatter(const int* __restrict__ src, const int* __restrict__ dst,
                                                 const float* __restrict__ w, const int* __restrict__ offs,
                                                 int* __restrict__ cursor, int* __restrict__ csr_src,
                                                 float* __restrict__ csr_w) {
  int e = blockIdx.x * 256 + threadIdx.x;
  if (e < NE) {
    int d = dst[e];
    int slot = offs[d] + atomicAdd(&cursor[d], 1);
    csr_src[slot] = src[e];
    csr_w[slot] = w[e];
  }
}

// ---------------- prep: both layers' fused weights + attn rows + mlp cvt ----------------
__global__ __launch_bounds__(256) void k_prep(const float* __restrict__ fc_w, const float* __restrict__ ofc_w,
                                              const float* __restrict__ al, const float* __restrict__ ar,
                                              const float* __restrict__ mlp_w,
                                              f16* __restrict__ fwh2, f16* __restrict__ alfh2,
                                              f16* __restrict__ mlph) {
  int r = blockIdx.x;
  int d = threadIdx.x;
  if (r < 512) {
    int l = r >> 8, rr = r & 255;
    int h = rr >> 6, o = rr & 63;
    const float* fcl = fc_w + (size_t)l * 65536;
    const float* ow = ofc_w + (size_t)l * 4096;
    float acc = 0.f;
    for (int f = 0; f < 64; ++f)
      acc = fmaf(ow[(o << 6) + f], fcl[(((h << 6) + f) << 8) + d], acc);
    fwh2[((size_t)l << 16) + (rr << 8) + d] = (f16)acc;
  } else if (r < 544) {
    int rr = r - 512;
    int l = rr >> 4, q = rr & 15;
    const float* fcl = fc_w + (size_t)l * 65536;
    float acc = 0.f;
    if (q < 8) {
      int h = q & 3;
      const float* a = ((q < 4) ? al : ar) + (size_t)l * NH * 64;
      for (int f = 0; f < 64; ++f)
        acc = fmaf(a[(h << 6) + f], fcl[(((h << 6) + f) << 8) + d], acc);
    }
    alfh2[((size_t)l << 12) + (q << 8) + d] = (f16)acc;
  } else {
    int i = (r - 544) * 256 + d;     // 32768 quads
    float4 v = *(const float4*)(mlp_w + (size_t)i * 4);
    H4 h;
    h.h[0] = (f16)v.x; h.h[1] = (f16)v.y; h.h[2] = (f16)v.z; h.h[3] = (f16)v.w;
    *(uint2*)(mlph + (size_t)i * 4) = h.u;
  }
}

// ---------------- MFMA fp16 GEMM, 64x128 tile, K-STEP 64 (+el/er fusion, +fp32 cvt) ----------------
// BK=64 halves barrier count (R17: -3.5us). Epilogue = R14-proven (non-swapped).
template<int OUTH, int EL, int CVT>
__global__ __launch_bounds__(256) void k_gemm_f16(
    const void* __restrict__ A, int lda, int K,
    const f16* __restrict__ W,
    const float* __restrict__ bias,
    void* __restrict__ outp, int ldo,
    const f16* __restrict__ alfh, float* __restrict__ el2, float* __restrict__ er2)
{
  __shared__ __align__(16) f16 As[64 * 64];    // 8KB
  __shared__ __align__(16) f16 Bs[128 * 64];   // 16KB
  const int tid = threadIdx.x;
  const int lane = tid & 63;
  const int w = tid >> 6;
  const int wr = w >> 1, wc = w & 1;
  const int ra0 = blockIdx.x * 64;
  const int c0 = blockIdx.y * 128;
  const int l8r = lane >> 3;           // 0..7 row within 8-row panel
  const int l8o = (lane & 7) * 8;      // 0..56 k-offset (halfs)

  f32x4 acc[2][4];
#pragma unroll
  for (int mr = 0; mr < 2; ++mr)
#pragma unroll
    for (int nr = 0; nr < 4; ++nr) acc[mr][nr] = (f32x4)0.f;
  f32x4 accel[2];
  accel[0] = (f32x4)0.f; accel[1] = (f32x4)0.f;
  const bool doEl = EL && (blockIdx.y == 0) && (wc == 0);

  const int fr = lane & 15;
  const int fg = (lane >> 4) * 8;

  for (int k0 = 0; k0 < K; k0 += 64) {
    if (CVT) {
      // reg-staged fp32 -> fp16; chunk c covers (row=c>>3, koct=c&7), dest As+c*8
      const float* sf = (const float*)A;
#pragma unroll
      for (int i = 0; i < 2; ++i) {
        int chunk = tid + i * 256;           // 512 chunks of 8 halfs
        int row = chunk >> 3;
        int kk = k0 + (chunk & 7) * 8;
        const float* ps = (kk < 128) ? sf + (size_t)(ra0 + row) * 128 + kk
                                     : sf + (size_t)(NM + ra0 + row) * 128 + (kk - 128);
        float4 p0 = *(const float4*)ps;
        float4 p1 = *(const float4*)(ps + 4);
        half8 hv;
        hv[0] = (f16)p0.x; hv[1] = (f16)p0.y; hv[2] = (f16)p0.z; hv[3] = (f16)p0.w;
        hv[4] = (f16)p1.x; hv[5] = (f16)p1.y; hv[6] = (f16)p1.z; hv[7] = (f16)p1.w;
        *(half8*)(As + chunk * 8) = hv;
      }
    } else {
      const f16* Af = (const f16*)A;
      // wave w stages rows 16w..16w+15 (2 issues of 8 rows x 128B)
      gload_lds16(Af + (size_t)(ra0 + 16 * w + l8r) * lda + k0 + l8o, As + w * 1024);
      gload_lds16(Af + (size_t)(ra0 + 16 * w + 8 + l8r) * lda + k0 + l8o, As + w * 1024 + 512);
    }
    // wave w stages cols 32w..32w+31 (4 issues of 8 cols x 128B)
#pragma unroll
    for (int j = 0; j < 4; ++j)
      gload_lds16(W + (size_t)(c0 + 32 * w + j * 8 + l8r) * K + k0 + l8o,
                  Bs + w * 2048 + j * 512);
    __syncthreads();

#pragma unroll
    for (int kk = 0; kk < 2; ++kk) {
      half8 af[2], bf[4];
#pragma unroll
      for (int mr = 0; mr < 2; ++mr)
        af[mr] = *(const half8*)(As + (wr * 32 + mr * 16 + fr) * 64 + kk * 32 + fg);
#pragma unroll
      for (int nr = 0; nr < 4; ++nr)
        bf[nr] = *(const half8*)(Bs + (wc * 64 + nr * 16 + fr) * 64 + kk * 32 + fg);
#pragma unroll
      for (int mr = 0; mr < 2; ++mr)
#pragma unroll
        for (int nr = 0; nr < 4; ++nr)
          acc[mr][nr] = __builtin_amdgcn_mfma_f32_16x16x32_f16(af[mr], bf[nr], acc[mr][nr], 0, 0, 0);
      if (doEl) {
        half8 bal = *(const half8*)(alfh + fr * 256 + k0 + kk * 32 + fg);   // L1-hot 8KB
#pragma unroll
        for (int mr = 0; mr < 2; ++mr)
          accel[mr] = __builtin_amdgcn_mfma_f32_16x16x32_f16(af[mr], bal, accel[mr], 0, 0, 0);
      }
    }
    __syncthreads();
  }

  const int r0 = (lane >> 4) * 4;
#pragma unroll
  for (int nr = 0; nr < 4; ++nr) {
    int col = c0 + wc * 64 + nr * 16 + fr;
    float bv = bias ? bias[col] : 0.f;
#pragma unroll
    for (int mr = 0; mr < 2; ++mr) {
      f32x4 v = acc[mr][nr];
#pragma unroll
      for (int r = 0; r < 4; ++r) {
        int ra = ra0 + wr * 32 + mr * 16 + r0 + r;
        float val = v[r] + bv;
        if (OUTH) ((f16*)outp)[(size_t)ra * ldo + col] = (f16)val;
        else      ((float*)outp)[(size_t)ra * ldo + col] = val;
      }
    }
  }
  if (doEl && fr < 8) {
#pragma unroll
    for (int mr = 0; mr < 2; ++mr) {
#pragma unroll
      for (int r = 0; r < 4; ++r) {
        int ra = ra0 + wr * 32 + mr * 16 + r0 + r;
        int n = ra % NN, b = ra / NN;
        int tb = (n << 4) + (b << 2);
        float val = accel[mr][r];
        if (fr < 4) el2[tb + fr] = val;
        else        er2[tb + (fr - 4)] = val;
      }
    }
  }
}

// ---------------- fused softmax + aggregate: wave per (n,b) ----------------
// R18-proven configuration: 8 edges/iter, 4 independent dwordx4 gathers in flight
// (MLP ladder measured: 2->4 outstanding = -9.3us; 4->8 = +11us regress. 4 is optimal.)
// Zero-filled 64-slot staging makes full 8-edge groups tail-safe (alpha=0, src=0).
__global__ __launch_bounds__(256) void k_edge8(
    const f16* __restrict__ featW_b, const float* __restrict__ el2, const float* __restrict__ er2,
    const int* __restrict__ csr_src, const float* __restrict__ csr_w,
    const int* __restrict__ offs, const float* __restrict__ b2, f16* __restrict__ outh)
{
  __shared__ __align__(16) unsigned aalp[4][64][4];  // [wave][edge][head] splat pairs
  __shared__ unsigned asrc[4][64];
  __shared__ float aw[4][64];
  __shared__ float sls[4][4];
  __shared__ float sinvs[4][4];
  const int t = threadIdx.x;
  const int w = t >> 6, lane = t & 63;
  const int b = blockIdx.x & 3;
  const int n = (blockIdx.x >> 2) * 4 + w;
  const int s0 = offs[n], s1 = offs[n + 1];
  const int es = lane >> 2;            // 0..15 edge slot
  const int sh = lane & 3;             // head
  const float erv = er2[(n << 4) + (b << 2) + sh];
  const int hl = lane & 31;            // lane within half
  const int eh = lane >> 5;            // which edge of the pair
  const int h8 = hl >> 3;              // head (8 ch/lane)
  const int ch0 = hl << 3;             // first channel owned
  const f16* fW = featW_b + ((size_t)b * NN << 8);

  float m = -INFINITY, srun = 0.f;
  h2 a0 = {(f16)0.f, (f16)0.f}, a1 = a0, a2 = a0, a3 = a0;

  for (int c0 = s0; c0 < s1; c0 += 64) {
    const int csz = min(64, s1 - c0);
    // unconditional zero-fill staging (tail-safe)
    unsigned sv = 0;
    float wv = 0.f;
    if (lane < csz) {
      sv = (unsigned)csr_src[c0 + lane];
      wv = csr_w[c0 + lane];
    }
    asrc[w][lane] = sv;
    aw[w][lane] = wv;
    // ---- score phase ----
    float sc[4];
#pragma unroll
    for (int i = 0; i < 4; ++i) {
      int e = es + 16 * i;
      if (e < csz) {
        int src = (int)asrc[w][e];
        float x = el2[(src << 4) + (b << 2) + sh] + erv;
        x = (x > 0.f) ? x : 0.1f * x;
        sc[i] = x * aw[w][e];
      } else sc[i] = -INFINITY;
    }
    float mc = fmaxf(fmaxf(sc[0], sc[1]), fmaxf(sc[2], sc[3]));
#pragma unroll
    for (int k = 4; k <= 32; k <<= 1) mc = fmaxf(mc, __shfl_xor(mc, k));
    float mn = fmaxf(m, mc);
    float sl = (m == -INFINITY) ? 0.f : __expf(m - mn);
    float ps = 0.f;
#pragma unroll
    for (int i = 0; i < 4; ++i) {
      int e = es + 16 * i;
      float a = (e < csz) ? __expf(sc[i] - mn) : 0.f;
      ps += a;
      f16 ah = (f16)a;
      U2H sp; sp.h[0] = ah; sp.h[1] = ah;
      aalp[w][e][sh] = sp.u;           // all 64 slots written -> tail-safe
    }
#pragma unroll
    for (int k = 4; k <= 32; k <<= 1) ps += __shfl_xor(ps, k);
    srun = srun * sl + ps;
    m = mn;
    if (es == 0) sls[w][sh] = sl;      // same-wave LDS handoff (no barrier)
    // ---- aggregate: 8 edges/iter, 4 independent gathers in flight ----
    float slA = sls[w][h8];
    f16 slh = (f16)slA;
    h2 slv = {slh, slh};
    a0 *= slv; a1 *= slv; a2 *= slv; a3 *= slv;
    for (int e = 0; e < csz; e += 8) {
      const int e0 = e + eh, e1 = e + 2 + eh, e2 = e + 4 + eh, e3 = e + 6 + eh;
      unsigned su0 = asrc[w][e0], su1 = asrc[w][e1], su2 = asrc[w][e2], su3 = asrc[w][e3];
      U2H al0, al1, al2, al3;
      al0.u = aalp[w][e0][h8]; al1.u = aalp[w][e1][h8];
      al2.u = aalp[w][e2][h8]; al3.u = aalp[w][e3][h8];
      U4H f0, f1, f2, f3;
      f0.u = *(const uint4*)(fW + ((size_t)su0 << 8) + ch0);
      f1.u = *(const uint4*)(fW + ((size_t)su1 << 8) + ch0);
      f2.u = *(const uint4*)(fW + ((size_t)su2 << 8) + ch0);
      f3.u = *(const uint4*)(fW + ((size_t)su3 << 8) + ch0);
      a0 += f0.h[0] * al0.h; a1 += f0.h[1] * al0.h; a2 += f0.h[2] * al0.h; a3 += f0.h[3] * al0.h;
      a0 += f1.h[0] * al1.h; a1 += f1.h[1] * al1.h; a2 += f1.h[2] * al1.h; a3 += f1.h[3] * al1.h;
      a0 += f2.h[0] * al2.h; a1 += f2.h[1] * al2.h; a2 += f2.h[2] * al2.h; a3 += f2.h[3] * al2.h;
      a0 += f3.h[0] * al3.h; a1 += f3.h[1] * al3.h; a2 += f3.h[2] * al3.h; a3 += f3.h[3] * al3.h;
    }
  }
  // combine the two half-wave edge streams
  U2H u0, u1, u2, u3;
  u0.h = a0; u1.h = a1; u2.h = a2; u3.h = a3;
  U2H p0, p1, p2, p3;
  p0.u = (unsigned)__shfl_xor((int)u0.u, 32);
  p1.u = (unsigned)__shfl_xor((int)u1.u, 32);
  p2.u = (unsigned)__shfl_xor((int)u2.u, 32);
  p3.u = (unsigned)__shfl_xor((int)u3.u, 32);
  a0 += p0.h; a1 += p1.h; a2 += p2.h; a3 += p3.h;

  float invs = (s1 > s0) ? 1.f / srun : 0.f;     // uniform across sh-group lanes
  if (es == 0) sinvs[w][sh] = invs;

  if (lane < 32) {
    const float invv = sinvs[w][h8];
    const float4 bv0 = *(const float4*)(b2 + ((hl & 7) << 3));
    const float4 bv1 = *(const float4*)(b2 + ((hl & 7) << 3) + 4);
    H4 o01, o23;
    o01.h[0] = (f16)fmaxf(fmaf((float)a0[0], invv, bv0.x), 0.f);
    o01.h[1] = (f16)fmaxf(fmaf((float)a0[1], invv, bv0.y), 0.f);
    o01.h[2] = (f16)fmaxf(fmaf((float)a1[0], invv, bv0.z), 0.f);
    o01.h[3] = (f16)fmaxf(fmaf((float)a1[1], invv, bv0.w), 0.f);
    o23.h[0] = (f16)fmaxf(fmaf((float)a2[0], invv, bv1.x), 0.f);
    o23.h[1] = (f16)fmaxf(fmaf((float)a2[1], invv, bv1.y), 0.f);
    o23.h[2] = (f16)fmaxf(fmaf((float)a3[0], invv, bv1.z), 0.f);
    o23.h[3] = (f16)fmaxf(fmaf((float)a3[1], invv, bv1.w), 0.f);
    uint4 ov;
    ov.x = o01.u.x; ov.y = o01.u.y; ov.z = o23.u.x; ov.w = o23.u.y;
    *(uint4*)(outh + ((size_t)(b * NN + n) << 9) + ch0) = ov;
  }
}

// ---------------- launch ----------------
extern "C" void kernel_launch(void* const* d_in, const int* in_sizes, int n_in,
                              void* d_out, int out_size, void* d_ws, size_t ws_size,
                              hipStream_t stream) {
  const float* sol    = (const float*)d_in[0];
  const float* w      = (const float*)d_in[1];
  const float* fc_w   = (const float*)d_in[2];
  const float* attn_l = (const float*)d_in[3];
  const float* attn_r = (const float*)d_in[4];
  const float* ofc_w  = (const float*)d_in[5];
  const float* ofc_b  = (const float*)d_in[6];
  const float* mlp_w  = (const float*)d_in[7];
  const float* mlp_b  = (const float*)d_in[8];
  const int*   d_src  = (const int*)d_in[9];
  const int*   d_dst  = (const int*)d_in[10];
  float* out = (float*)d_out;

  char* p = (char*)d_ws;
  auto alloc = [&](size_t bytes) { char* r = p; p += (bytes + 255) & ~(size_t)255; return r; };
  f16*   out01h  = (f16*)alloc((size_t)(NM + 128) * 512 * 2);
  f16*   featWb  = (f16*)alloc((size_t)NM * 256 * 2);          // [b*NN+n][256] row-major
  f16*   fwh2    = (f16*)alloc((size_t)2 * ND * ND * 2);
  f16*   alfh2   = (f16*)alloc((size_t)2 * 16 * ND * 2);       // rows 8-15 zero
  f16*   mlph    = (f16*)alloc((size_t)ND * 512 * 2);
  float* el2     = (float*)alloc((size_t)NT * 4);              // [NN][16]
  float* er2     = (float*)alloc((size_t)NT * 4);
  int*   degcur  = (int*)alloc((size_t)(2 * NN) * 4);          // deg[NN] + cursor[NN], one memset
  int*   deg     = degcur;
  int*   cursor  = degcur + NN;
  int*   offs    = (int*)alloc((size_t)(NN + 1) * 4);
  int*   csr_src = (int*)alloc((size_t)NE * 4);
  float* csr_w   = (float*)alloc((size_t)NE * 4);
  if ((size_t)(p - (char*)d_ws) > ws_size) return;

  hipMemsetAsync(degcur, 0, (size_t)(2 * NN) * 4, stream);
  k_deg<<<NE / 256, 256, 0, stream>>>(d_dst, deg);
  k_scan2<<<1, 1024, 0, stream>>>(deg, offs);
  k_scatter<<<NE / 256, 256, 0, stream>>>(d_src, d_dst, w, offs, cursor, csr_src, csr_w);

  k_prep<<<672, 256, 0, stream>>>(fc_w, ofc_w, attn_l, attn_r, mlp_w, fwh2, alfh2, mlph);

  for (int l = 0; l < 2; ++l) {
    const f16* fwh  = fwh2 + ((size_t)l << 16);
    const f16* alfh = alfh2 + ((size_t)l << 12);
    if (l == 0) {
      k_gemm_f16<1, 1, 1><<<dim3(NM / 64, ND / 128), 256, 0, stream>>>(
          sol, 128, 256, fwh, nullptr, featWb, 256, alfh, el2, er2);
    } else {
      k_gemm_f16<1, 1, 0><<<dim3(NM / 64, ND / 128), 256, 0, stream>>>(
          out01h, 512, 256, fwh, nullptr, featWb, 256, alfh, el2, er2);
    }
    k_edge8<<<(NN / 4) * 4, 256, 0, stream>>>(featWb, el2, er2, csr_src, csr_w, offs,
                                              ofc_b + (size_t)l * 64, out01h + (l == 0 ? 0 : 256));
  }

  k_gemm_f16<0, 0, 0><<<dim3(NM / 64, ND / 128), 256, 0, stream>>>(
      out01h, 512, 512, mlph, mlp_b, out, 256, nullptr, nullptr, nullptr);
}